// Round 1
// baseline (307.799 us; speedup 1.0000x reference)
//
#include <hip/hip_runtime.h>

// Problem constants (fixed by the reference).
constexpr int IN_CH = 4;
constexpr int KS    = 40;
constexpr int L_IN  = 8192;
constexpr int L_OUT = L_IN - KS + 1;   // 8153
constexpr int NF    = 600;
constexpr int BATCH = 32;
constexpr int CHUNK = 1024;            // 256 threads * 4 elements

// Each filter k of the weight tensor [600, 4, 40] has exactly 2 nonzero taps.
// out[b,k,l] = sum_taps w * x[b, c, l + p].
// Write-BW-bound: 626 MB output per call; x (4 MB) is cache-resident.
__global__ __launch_bounds__(256) void fdc_kernel(const float* __restrict__ x,
                                                  const float* __restrict__ w,
                                                  float* __restrict__ out) {
    const int k = blockIdx.y;   // filter
    const int b = blockIdx.z;   // batch

    // --- Extract nonzero taps of filter k into LDS (2 expected, room for 8) ---
    __shared__ int   s_cnt;
    __shared__ int   s_off[8];   // c * L_IN + p  (offset into this batch's x)
    __shared__ float s_w[8];
    if (threadIdx.x == 0) s_cnt = 0;
    __syncthreads();
    if (threadIdx.x < IN_CH * KS) {
        const float wv = w[k * IN_CH * KS + threadIdx.x];
        if (wv != 0.0f) {
            const int slot = atomicAdd(&s_cnt, 1);
            s_off[slot] = (threadIdx.x / KS) * L_IN + (threadIdx.x % KS);
            s_w[slot]   = wv;
        }
    }
    __syncthreads();
    const int nt = s_cnt;

    const float* xb   = x + (size_t)b * IN_CH * L_IN;
    const int    base = blockIdx.x * CHUNK;

    float acc[4] = {0.f, 0.f, 0.f, 0.f};
    for (int t = 0; t < nt; ++t) {
        const float* xr = xb + s_off[t];
        const float  wv = s_w[t];
#pragma unroll
        for (int j = 0; j < 4; ++j) {
            const int l = base + threadIdx.x + j * 256;
            if (l < L_OUT) acc[j] += wv * xr[l];
        }
    }

    float* orow = out + ((size_t)b * NF + k) * L_OUT;
#pragma unroll
    for (int j = 0; j < 4; ++j) {
        const int l = base + threadIdx.x + j * 256;
        if (l < L_OUT) orow[l] = acc[j];
    }
}

extern "C" void kernel_launch(void* const* d_in, const int* in_sizes, int n_in,
                              void* d_out, int out_size, void* d_ws, size_t ws_size,
                              hipStream_t stream) {
    const float* x = (const float*)d_in[0];   // [32, 4, 8192] fp32
    const float* w = (const float*)d_in[1];   // [600, 4, 40]  fp32
    float*       o = (float*)d_out;           // [32, 600, 8153] fp32

    const int n_chunks = (L_OUT + CHUNK - 1) / CHUNK;   // 8
    dim3 grid(n_chunks, NF, BATCH);
    fdc_kernel<<<grid, 256, 0, stream>>>(x, w, o);
}

// Round 2
// 180.224 us; speedup vs baseline: 1.7079x; 1.7079x over previous
//
#include <hip/hip_runtime.h>

// Problem constants (fixed by the reference).
constexpr int IN_CH = 4;
constexpr int KS    = 40;
constexpr int L_IN  = 8192;
constexpr int L_OUT = L_IN - KS + 1;   // 8153
constexpr int NF    = 600;
constexpr int BATCH = 32;
constexpr int CHUNK = 1024;            // outputs per block along L
constexpr int KPB   = 60;              // filters per block
constexpr int NKG   = NF / KPB;        // 10 k-groups
constexpr int XST   = CHUNK + KS;      // 1064 floats/channel staged (16B multiple)

// Each filter has exactly 2 nonzero taps: out[b,k,l] = w0*x[b,c0,l+p0] + w1*x[b,c1,l+p1].
// Stage the x chunk (4 ch x 1064 f32 = 17 KB) in LDS once, reuse across 60 filters:
// global reads drop 30x vs per-filter blocks; kernel becomes write-BW-bound.
__global__ __launch_bounds__(256) void fdc_kernel(const float* __restrict__ x,
                                                  const float* __restrict__ w,
                                                  float* __restrict__ out) {
    const int base = blockIdx.x * CHUNK;     // output l offset
    const int k0   = blockIdx.y * KPB;       // first filter of this group
    const int b    = blockIdx.z;             // batch

    __shared__ float s_x[IN_CH * XST];
    __shared__ int   s_cnt[KPB];
    __shared__ int   s_toff[KPB][2];
    __shared__ float s_tw[KPB][2];

    // --- init tap tables ---
    for (int i = threadIdx.x; i < KPB; i += 256) {
        s_cnt[i] = 0;
        s_toff[i][0] = 0; s_toff[i][1] = 0;
        s_tw[i][0]  = 0.f; s_tw[i][1]  = 0.f;
    }
    __syncthreads();

    // --- stage x chunk into LDS (float4 loads; x rows are 16B-aligned, base%1024==0) ---
    const float* xb = x + (size_t)b * IN_CH * L_IN;
    const int n4 = min(XST / 4, (L_IN - base) / 4);   // valid float4s per channel
    for (int i = threadIdx.x; i < IN_CH * (XST / 4); i += 256) {
        const int c  = i / (XST / 4);
        const int i4 = i % (XST / 4);
        if (i4 < n4) {
            const float4 v = *reinterpret_cast<const float4*>(xb + c * L_IN + base + i4 * 4);
            *reinterpret_cast<float4*>(&s_x[c * XST + i4 * 4]) = v;
        }
    }

    // --- extract nonzero taps for the 60 filters of this group ---
    const float* wg = w + (size_t)k0 * IN_CH * KS;
    for (int i = threadIdx.x; i < KPB * IN_CH * KS; i += 256) {
        const float wv = wg[i];
        if (wv != 0.0f) {
            const int kk = i / (IN_CH * KS);
            const int r  = i % (IN_CH * KS);
            const int c  = r / KS;
            const int p  = r % KS;
            const int slot = atomicAdd(&s_cnt[kk], 1);
            if (slot < 2) {
                s_toff[kk][slot] = c * XST + p;
                s_tw[kk][slot]   = wv;
            }
        }
    }
    __syncthreads();

    // --- canonicalize tap order (deterministic output regardless of atomic order) ---
    for (int kk = threadIdx.x; kk < KPB; kk += 256) {
        if (s_cnt[kk] >= 2 && s_toff[kk][0] > s_toff[kk][1]) {
            const int   t0 = s_toff[kk][0]; s_toff[kk][0] = s_toff[kk][1]; s_toff[kk][1] = t0;
            const float v0 = s_tw[kk][0];   s_tw[kk][0]   = s_tw[kk][1];   s_tw[kk][1]   = v0;
        }
    }
    __syncthreads();

    // --- compute: 60 filters x 1024 outputs, all x reads from LDS ---
    const int nvalid = L_OUT - base;          // < CHUNK only for the last chunk
    float* ob = out + ((size_t)b * NF + k0) * L_OUT + base;
    for (int kk = 0; kk < KPB; ++kk) {
        const int   o0 = s_toff[kk][0];
        const int   o1 = s_toff[kk][1];
        const float w0 = s_tw[kk][0];
        const float w1 = s_tw[kk][1];
        float* orow = ob + (size_t)kk * L_OUT;
#pragma unroll
        for (int j = 0; j < 4; ++j) {
            const int l = threadIdx.x + j * 256;
            if (l < nvalid) orow[l] = w0 * s_x[o0 + l] + w1 * s_x[o1 + l];
        }
    }
}

extern "C" void kernel_launch(void* const* d_in, const int* in_sizes, int n_in,
                              void* d_out, int out_size, void* d_ws, size_t ws_size,
                              hipStream_t stream) {
    const float* x = (const float*)d_in[0];   // [32, 4, 8192] fp32
    const float* w = (const float*)d_in[1];   // [600, 4, 40]  fp32
    float*       o = (float*)d_out;           // [32, 600, 8153] fp32

    dim3 grid((L_OUT + CHUNK - 1) / CHUNK, NKG, BATCH);   // (8, 10, 32)
    fdc_kernel<<<grid, 256, 0, stream>>>(x, w, o);
}